// Round 2
// baseline (2105.328 us; speedup 1.0000x reference)
//
#include <hip/hip_runtime.h>
#include <hip/hip_bf16.h>
#include <math.h>

// ---------------- constants ----------------
#define TSEQ 2048
#define HID  2048
#define QL   512
#define KVL  512
#define DR   64
#define DN   128
#define DVV  128
#define NHH  16
#define IDXH 16
#define IDXD 128
#define TOPK 512
#define INTER 8192
#define STEP1_N  1232
#define STEP1_NP 1280
#define HGRP 4   // heads per attention group (4 groups of 4)

#define NEG_FLT_MAX (-3.402823466e38f)

typedef __hip_bfloat16 bf16;
typedef unsigned int u32;
typedef __attribute__((ext_vector_type(8))) short short8;
typedef __attribute__((ext_vector_type(4))) float f32x4;

__device__ __forceinline__ float bf2f(bf16 x) { return __bfloat162float(x); }
__device__ __forceinline__ bf16  f2bf(float x){ return __float2bfloat16(x); }

// ---------------- block reductions ----------------
__device__ __forceinline__ float block_sum(float v, float* red, int tid) {
  __syncthreads();
#pragma unroll
  for (int o = 32; o > 0; o >>= 1) v += __shfl_down(v, o, 64);
  if ((tid & 63) == 0) red[tid >> 6] = v;
  __syncthreads();
  return red[0] + red[1] + red[2] + red[3];
}
__device__ __forceinline__ float block_max(float v, float* red, int tid) {
  __syncthreads();
#pragma unroll
  for (int o = 32; o > 0; o >>= 1) v = fmaxf(v, __shfl_down(v, o, 64));
  if ((tid & 63) == 0) red[tid >> 6] = v;
  __syncthreads();
  return fmaxf(fmaxf(red[0], red[1]), fmaxf(red[2], red[3]));
}

// ---------------- w_uv (16,512,128) -> w_uv_t (16,128,512) bf16 ----------------
__global__ void cvt_uv_t(const float* __restrict__ in, bf16* __restrict__ out) {
  long n = (long)16 * 512 * 128;
  long i = (long)blockIdx.x * blockDim.x + threadIdx.x;
  long stride = (long)gridDim.x * blockDim.x;
  for (; i < n; i += stride) {
    long h = i >> 16;
    long k = (i >> 7) & 511;
    long v = i & 127;
    out[h * 65536 + v * 512 + k] = f2bf(in[i]);
  }
}

// ---------------- r1 = hs + res ; h = rmsnorm(r1)*ln1 ----------------
__global__ __launch_bounds__(256) void r1_rms(
    const float* __restrict__ hs, const float* __restrict__ res,
    const float* __restrict__ w, float* __restrict__ r1out, bf16* __restrict__ hb) {
  const int t = blockIdx.x, tid = threadIdx.x;
  __shared__ float red[4];
  float loc[8];
  float ss = 0.f;
  const long base = (long)t * HID;
#pragma unroll
  for (int e = 0; e < 8; e++) {
    int i = e * 256 + tid;
    float v = hs[base + i] + res[base + i];
    loc[e] = v; ss += v * v;
    r1out[base + i] = v;
  }
  ss = block_sum(ss, red, tid);
  float rs = rsqrtf(ss / (float)HID + 1e-6f);
#pragma unroll
  for (int e = 0; e < 8; e++) { int i = e * 256 + tid; hb[base + i] = f2bf(loc[e] * rs * w[i]); }
}

// ---------------- rmsnorm(r2)*ln2 -> h3 bf16 ----------------
__global__ __launch_bounds__(256) void rms_h3(
    const float* __restrict__ r2, const float* __restrict__ w, bf16* __restrict__ h3b) {
  const int t = blockIdx.x, tid = threadIdx.x;
  __shared__ float red[4];
  float loc[8];
  float ss = 0.f;
  const long base = (long)t * HID;
#pragma unroll
  for (int e = 0; e < 8; e++) {
    int i = e * 256 + tid;
    float v = r2[base + i];
    loc[e] = v; ss += v * v;
  }
  ss = block_sum(ss, red, tid);
  float rs = rsqrtf(ss / (float)HID + 1e-6f);
#pragma unroll
  for (int e = 0; e < 8; e++) { int i = e * 256 + tid; h3b[base + i] = f2bf(loc[e] * rs * w[i]); }
}

// ---------------- postprocess step1 row ----------------
__global__ __launch_bounds__(256) void postprocess_step1(
    const float* __restrict__ step1, const int* __restrict__ positions,
    const float* __restrict__ q_ln, const float* __restrict__ kv_ln,
    bf16* __restrict__ q_cn, bf16* __restrict__ kv_cn,
    bf16* __restrict__ idx_kb, float* __restrict__ idx_wf,
    bf16* __restrict__ kfull) {
  const int t = blockIdx.x, tid = threadIdx.x;
  __shared__ float red[4];
  const float* row = step1 + (long)t * STEP1_NP;
  float q0 = row[tid], q1 = row[256 + tid];
  float ssq = q0 * q0 + q1 * q1;
  ssq = block_sum(ssq, red, tid);
  float rsq = rsqrtf(ssq / (float)QL + 1e-6f);
  q_cn[(long)t * QL + tid]       = f2bf(q0 * rsq * q_ln[tid]);
  q_cn[(long)t * QL + 256 + tid] = f2bf(q1 * rsq * q_ln[256 + tid]);
  float k0v = row[512 + tid], k1v = row[768 + tid];
  float ssk = k0v * k0v + k1v * k1v;
  ssk = block_sum(ssk, red, tid);
  float rsk = rsqrtf(ssk / (float)KVL + 1e-6f);
  kv_cn[(long)t * KVL + tid]       = f2bf(k0v * rsk * kv_ln[tid]);
  kv_cn[(long)t * KVL + 256 + tid] = f2bf(k1v * rsk * kv_ln[256 + tid]);
  if (tid < 128) idx_kb[(long)t * IDXD + tid] = f2bf(row[1088 + tid]);
  if (tid < 16) idx_wf[(long)t * IDXH + tid] = row[1216 + tid];
  if (tid < 32) {
    const int j = tid;
    float x1 = row[1024 + j], x2 = row[1056 + j];
    float p = (float)positions[t];
    float inv = powf(10000.f, -(float)j * (1.f / 32.f));
    float ang = p * inv;
    float c = cosf(ang), s = sinf(ang);
    bf16 o1 = f2bf(x1 * c - x2 * s), o2 = f2bf(x1 * s + x2 * c);
#pragma unroll
    for (int h = 0; h < NHH; h++) {
      kfull[(long)h * TSEQ * 192 + (long)t * 192 + 128 + j] = o1;
      kfull[(long)h * TSEQ * 192 + (long)t * 192 + 160 + j] = o2;
    }
  }
}

// ---------------- rope on q_pe part of qf (in place, bf16) ----------------
__global__ __launch_bounds__(256) void rope_q(bf16* __restrict__ qf, const int* __restrict__ positions) {
  const int t = blockIdx.x, tid = threadIdx.x;
  const float p = (float)positions[t];
#pragma unroll
  for (int e = 0; e < 2; e++) {
    int id = e * 256 + tid;
    int h = id >> 5, j = id & 31;
    long o = (long)t * 3072 + h * 192 + 128;
    float x1 = bf2f(qf[o + j]), x2 = bf2f(qf[o + 32 + j]);
    float inv = powf(10000.f, -(float)j * (1.f / 32.f));
    float ang = p * inv;
    float c = cosf(ang), s = sinf(ang);
    qf[o + j]      = f2bf(x1 * c - x2 * s);
    qf[o + 32 + j] = f2bf(x1 * s + x2 * c);
  }
}

// ---------------- generic bf16 GEMM: C = A(M,K;lda) * B(N,K;ldb)^T ----------------
// BF32: B is fp32 in global, converted to bf16 during LDS staging; rows >= N staged as 0.
enum { EPI_F32 = 0, EPI_BF16 = 1, EPI_ADD_F32 = 2, EPI_MASK_BF16 = 3, EPI_SILUMUL_BF16 = 4 };

template <int MODE, bool CSKIP, bool BF32>
__global__ __launch_bounds__(256) void gemm_bt(
    const bf16* __restrict__ A, const void* __restrict__ B, void* __restrict__ Cout,
    int N, int K, int lda, int ldb, int ldc,
    long az, long bz, long cz,
    const void* __restrict__ ex0, const float* __restrict__ ex1, float scale) {
  __shared__ __align__(16) bf16 As[128 * 64];
  __shared__ __align__(16) bf16 Bs[128 * 64];
  const int z = blockIdx.z;
  const int bm = blockIdx.x, bn = blockIdx.y;
  const int tid = threadIdx.x;
  const int lane = tid & 63, wave = tid >> 6;
  const int wm = wave >> 1, wn = wave & 1;
  const int quad = lane >> 4, l16 = lane & 15;
  const long cbase = cz * (long)z;

  if (CSKIP) {
    if (bn > bm) {  // fully masked upper-triangle tile
      const bf16 nb = f2bf(-INFINITY);
#pragma unroll
      for (int i = 0; i < 4; i++)
#pragma unroll
        for (int j = 0; j < 4; j++) {
          int r0 = bm * 128 + wm * 64 + i * 16 + quad * 4;
          int c = bn * 128 + wn * 64 + j * 16 + l16;
#pragma unroll
          for (int r = 0; r < 4; r++) ((bf16*)Cout)[cbase + (long)(r0 + r) * ldc + c] = nb;
        }
      return;
    }
  }

  const bf16* Ab = A + az * (long)z;

  f32x4 acc[4][4];
#pragma unroll
  for (int i = 0; i < 4; i++)
#pragma unroll
    for (int j = 0; j < 4; j++) acc[i][j] = (f32x4){0.f, 0.f, 0.f, 0.f};

  const int row_st = tid >> 3;       // 0..31
  const int col_st = (tid & 7) * 8;  // 0..56

  for (int k0 = 0; k0 < K; k0 += 64) {
#pragma unroll
    for (int r0 = 0; r0 < 128; r0 += 32) {
      *(short8*)&As[(r0 + row_st) * 64 + col_st] =
          *(const short8*)&Ab[(long)(bm * 128 + r0 + row_st) * lda + k0 + col_st];
    }
    if (BF32) {
      const float* Bf = (const float*)B + bz * (long)z;
#pragma unroll
      for (int r0 = 0; r0 < 128; r0 += 32) {
        const int br = bn * 128 + r0 + row_st;
        short8 v = {0, 0, 0, 0, 0, 0, 0, 0};
        if (br < N) {
          const f32x4 f0 = *(const f32x4*)&Bf[(long)br * ldb + k0 + col_st];
          const f32x4 f1 = *(const f32x4*)&Bf[(long)br * ldb + k0 + col_st + 4];
          union { bf16 b; short s; } cv;
#pragma unroll
          for (int q = 0; q < 4; q++) { cv.b = f2bf(f0[q]); v[q] = cv.s; }
#pragma unroll
          for (int q = 0; q < 4; q++) { cv.b = f2bf(f1[q]); v[4 + q] = cv.s; }
        }
        *(short8*)&Bs[(r0 + row_st) * 64 + col_st] = v;
      }
    } else {
      const bf16* Bb = (const bf16*)B + bz * (long)z;
#pragma unroll
      for (int r0 = 0; r0 < 128; r0 += 32) {
        *(short8*)&Bs[(r0 + row_st) * 64 + col_st] =
            *(const short8*)&Bb[(long)(bn * 128 + r0 + row_st) * ldb + k0 + col_st];
      }
    }
    __syncthreads();
#pragma unroll
    for (int kc = 0; kc < 2; kc++) {
      const int kofs = kc * 32 + quad * 8;
      short8 af[4], bfr[4];
#pragma unroll
      for (int i = 0; i < 4; i++) af[i] = *(const short8*)&As[(wm * 64 + i * 16 + l16) * 64 + kofs];
#pragma unroll
      for (int i = 0; i < 4; i++) bfr[i] = *(const short8*)&Bs[(wn * 64 + i * 16 + l16) * 64 + kofs];
#pragma unroll
      for (int i = 0; i < 4; i++)
#pragma unroll
        for (int j = 0; j < 4; j++)
          acc[i][j] = __builtin_amdgcn_mfma_f32_16x16x32_bf16(af[i], bfr[j], acc[i][j], 0, 0, 0);
    }
    __syncthreads();
  }

#pragma unroll
  for (int i = 0; i < 4; i++) {
    const int rb = bm * 128 + wm * 64 + i * 16 + quad * 4;
#pragma unroll
    for (int j = 0; j < 4; j++) {
      const int c = bn * 128 + wn * 64 + j * 16 + l16;
#pragma unroll
      for (int r = 0; r < 4; r++) {
        const int rg = rb + r;
        const float v = acc[i][j][r];
        const long cidx = cbase + (long)rg * ldc + c;
        if (MODE == EPI_F32) {
          ((float*)Cout)[cidx] = v;
        } else if (MODE == EPI_BF16) {
          ((bf16*)Cout)[cidx] = f2bf(v);
        } else if (MODE == EPI_ADD_F32) {
          ((float*)Cout)[cidx] = v + ((const float*)ex0)[(long)rg * ldc + c];
        } else if (MODE == EPI_MASK_BF16) {
          float o;
          if (c > rg || ((const float*)ex0)[(long)rg * 2048 + c] < ex1[rg]) o = -INFINITY;
          else o = v * scale;
          ((bf16*)Cout)[cidx] = f2bf(o);
        } else if (MODE == EPI_SILUMUL_BF16) {
          const float g = bf2f(((const bf16*)ex0)[(long)rg * ldc + c]);
          const float sg = g / (1.f + __expf(-g));
          ((bf16*)Cout)[cidx] = f2bf(sg * v);
        }
      }
    }
  }
}

// ---------------- fused indexer score ----------------
__global__ __launch_bounds__(256) void iscore_kernel(
    const bf16* __restrict__ q_idx, const bf16* __restrict__ idx_k,
    const float* __restrict__ idx_w, float* __restrict__ iscore) {
  __shared__ __align__(16) bf16 As[128 * 64];
  __shared__ __align__(16) bf16 Bs[128 * 128];
  __shared__ float Ws[128 * 16];
  const int bm = blockIdx.x, bn = blockIdx.y;
  const int tid = threadIdx.x;
  const int lane = tid & 63, wave = tid >> 6;
  const int wm = wave >> 1, wn = wave & 1;
  const int quad = lane >> 4, l16 = lane & 15;

  if (bn > bm) {
#pragma unroll
    for (int i = 0; i < 4; i++)
#pragma unroll
      for (int j = 0; j < 4; j++) {
        int r0 = bm * 128 + wm * 64 + i * 16 + quad * 4;
        int c = bn * 128 + wn * 64 + j * 16 + l16;
#pragma unroll
        for (int r = 0; r < 4; r++) iscore[(long)(r0 + r) * 2048 + c] = NEG_FLT_MAX;
      }
    return;
  }

  {
    const int rs = tid >> 4, cs = (tid & 15) * 8;
#pragma unroll
    for (int r0 = 0; r0 < 128; r0 += 16)
      *(short8*)&Bs[(r0 + rs) * 128 + cs] =
          *(const short8*)&idx_k[(long)(bn * 128 + r0 + rs) * IDXD + cs];
  }
#pragma unroll
  for (int e = 0; e < 8; e++) {
    int ii = e * 256 + tid;
    Ws[ii] = idx_w[(long)(bm * 128) * IDXH + ii];
  }

  float accT[4][4][4];
#pragma unroll
  for (int i = 0; i < 4; i++)
#pragma unroll
    for (int j = 0; j < 4; j++)
#pragma unroll
      for (int r = 0; r < 4; r++) accT[i][j][r] = 0.f;

  const int row_st = tid >> 3, col_st = (tid & 7) * 8;

  for (int h = 0; h < IDXH; h++) {
    f32x4 acc[4][4];
#pragma unroll
    for (int i = 0; i < 4; i++)
#pragma unroll
      for (int j = 0; j < 4; j++) acc[i][j] = (f32x4){0.f, 0.f, 0.f, 0.f};
    for (int kh = 0; kh < 128; kh += 64) {
      __syncthreads();
#pragma unroll
      for (int r0 = 0; r0 < 128; r0 += 32)
        *(short8*)&As[(r0 + row_st) * 64 + col_st] =
            *(const short8*)&q_idx[(long)(bm * 128 + r0 + row_st) * 2048 + h * 128 + kh + col_st];
      __syncthreads();
#pragma unroll
      for (int kc = 0; kc < 2; kc++) {
        const int kofs = kc * 32 + quad * 8;
        short8 af[4], bfr[4];
#pragma unroll
        for (int i = 0; i < 4; i++) af[i] = *(const short8*)&As[(wm * 64 + i * 16 + l16) * 64 + kofs];
#pragma unroll
        for (int i = 0; i < 4; i++) bfr[i] = *(const short8*)&Bs[(wn * 64 + i * 16 + l16) * 128 + kh + kofs];
#pragma unroll
        for (int i = 0; i < 4; i++)
#pragma unroll
          for (int j = 0; j < 4; j++)
            acc[i][j] = __builtin_amdgcn_mfma_f32_16x16x32_bf16(af[i], bfr[j], acc[i][j], 0, 0, 0);
      }
    }
    const float sc = 0.08838834764831845f;  // 128^-0.5
#pragma unroll
    for (int i = 0; i < 4; i++) {
      int rl = wm * 64 + i * 16 + quad * 4;
#pragma unroll
      for (int r = 0; r < 4; r++) {
        float w = Ws[(rl + r) * 16 + h];
#pragma unroll
        for (int j = 0; j < 4; j++) {
          float v = acc[i][j][r] * sc;
          v = v > 0.f ? v : 0.f;
          accT[i][j][r] += v * w;
        }
      }
    }
  }
#pragma unroll
  for (int i = 0; i < 4; i++) {
    int rb = bm * 128 + wm * 64 + i * 16 + quad * 4;
#pragma unroll
    for (int j = 0; j < 4; j++) {
      int c = bn * 128 + wn * 64 + j * 16 + l16;
#pragma unroll
      for (int r = 0; r < 4; r++) {
        int rg = rb + r;
        iscore[(long)rg * 2048 + c] = (c <= rg) ? accT[i][j][r] : NEG_FLT_MAX;
      }
    }
  }
}

// ---------------- exact k-th largest per row (radix select) ----------------
__global__ __launch_bounds__(256) void radix_topk(const float* __restrict__ iscore, float* __restrict__ thr) {
  __shared__ u32 keys[2048];
  __shared__ int hist[256];
  __shared__ u32 s_prefix;
  __shared__ int s_k;
  const int t = blockIdx.x, tid = threadIdx.x;
#pragma unroll
  for (int e = 0; e < 8; e++) {
    int i = e * 256 + tid;
    u32 b = __float_as_uint(iscore[(long)t * 2048 + i]);
    keys[i] = (b & 0x80000000u) ? ~b : (b | 0x80000000u);
  }
  if (tid == 0) { s_prefix = 0u; s_k = TOPK; }
  u32 prefmask = 0u;
  for (int pass = 0; pass < 4; pass++) {
    const int shift = 24 - pass * 8;
    hist[tid] = 0;
    __syncthreads();
    const u32 pref = s_prefix;
#pragma unroll
    for (int e = 0; e < 8; e++) {
      int i = e * 256 + tid;
      u32 key = keys[i];
      if ((key & prefmask) == pref) atomicAdd(&hist[(key >> shift) & 255], 1);
    }
    __syncthreads();
    if (tid == 0) {
      int k = s_k, d = 255;
      for (; d >= 0; d--) {
        int c = hist[d];
        if (k <= c) break;
        k -= c;
      }
      if (d < 0) d = 0;
      s_prefix = pref | ((u32)d << shift);
      s_k = k;
    }
    prefmask |= (0xFFu << shift);
    __syncthreads();
  }
  if (tid == 0) {
    u32 key = s_prefix;
    u32 b = (key & 0x80000000u) ? (key ^ 0x80000000u) : ~key;
    thr[t] = __uint_as_float(b);
  }
}

// ---------------- in-place row softmax on bf16 (G,T,T) ----------------
__global__ __launch_bounds__(256) void softmax_rows(bf16* __restrict__ p) {
  const int t = blockIdx.x, h = blockIdx.y, tid = threadIdx.x;
  __shared__ float red[4];
  bf16* pr = p + ((long)h * TSEQ + t) * TSEQ;
  float loc[8];
  float mx = -INFINITY;
#pragma unroll
  for (int e = 0; e < 8; e++) {
    float v = bf2f(pr[e * 256 + tid]);
    loc[e] = v;
    mx = fmaxf(mx, v);
  }
  mx = block_max(mx, red, tid);
  float sum = 0.f;
#pragma unroll
  for (int e = 0; e < 8; e++) {
    float d = loc[e] - mx;
    float v = (d < -80.f) ? 0.f : __expf(d);
    loc[e] = v;
    sum += v;
  }
  sum = block_sum(sum, red, tid);
  float inv = 1.f / sum;
#pragma unroll
  for (int e = 0; e < 8; e++) pr[e * 256 + tid] = f2bf(loc[e] * inv);
}

// ---------------- host ----------------
extern "C" void kernel_launch(void* const* d_in, const int* in_sizes, int n_in,
                              void* d_out, int out_size, void* d_ws, size_t ws_size,
                              hipStream_t stream) {
  (void)in_sizes; (void)n_in; (void)out_size; (void)ws_size;
  const int*   positions = (const int*)d_in[0];
  const float* hs        = (const float*)d_in[1];
  const float* res       = (const float*)d_in[2];
  const float* ln1       = (const float*)d_in[3];
  const float* ln2       = (const float*)d_in[4];
  const float* qln       = (const float*)d_in[5];
  const float* kvln      = (const float*)d_in[6];
  const float* w_step1   = (const float*)d_in[7];
  const float* w_wq_b    = (const float*)d_in[8];
  const float* w_q_b     = (const float*)d_in[9];
  const float* w_uk      = (const float*)d_in[10];
  const float* w_uv      = (const float*)d_in[11];
  const float* w_o       = (const float*)d_in[12];
  const float* w_gate    = (const float*)d_in[13];
  const float* w_up      = (const float*)d_in[14];
  const float* w_down    = (const float*)d_in[15];

  float* out_f = (float*)d_out;                    // (T,HID)
  float* r2    = out_f + (long)TSEQ * HID;         // (T,HID) — holds r1 until w_o GEMM

  // ---- workspace pool (~113 MB total, explicit aliasing) ----
  char* base = (char*)d_ws;
  size_t off = 0;
  auto alloc = [&](size_t bytes) -> char* {
    char* p = base + off;
    off += (bytes + 255) & ~(size_t)255;
    return p;
  };
  bf16*  w_uv_tb = (bf16*)alloc((size_t)16 * 128 * 512 * 2);       // 2.1 MB
  char*  regA    = alloc((size_t)TSEQ * HID * 2);                  // 8.4 MB: h_b -> h3_b
  float* step1   = (float*)alloc((size_t)TSEQ * STEP1_NP * 4);     // 10.5 MB
  bf16*  q_cn    = (bf16*)alloc((size_t)TSEQ * QL * 2);
  bf16*  kv_cn   = (bf16*)alloc((size_t)TSEQ * KVL * 2);
  bf16*  idx_kb  = (bf16*)alloc((size_t)TSEQ * IDXD * 2);
  float* idx_wf  = (float*)alloc((size_t)TSEQ * IDXH * 4);
  char*  regB    = alloc((size_t)TSEQ * 2048 * 2);                 // 8.4 MB: q_idx_b -> attn_b
  bf16*  qf_b    = (bf16*)alloc((size_t)TSEQ * 3072 * 2);          // 12.6 MB
  float* thr     = (float*)alloc((size_t)TSEQ * 4);
  // BIG region: [iscore | kfull | v_lat_t | p_g] — dead before MLP, aliased by gate/act
  char*  big     = alloc((size_t)16777216 + 12582912 + 8388608 + (size_t)HGRP * TSEQ * TSEQ * 2);
  float* iscore  = (float*)big;                                    // 16.8 MB
  bf16*  kfull   = (bf16*)(big + 16777216);                        // 12.6 MB  (16,T,192)
  bf16*  v_lat_t = (bf16*)(big + 16777216 + 12582912);             // 8.4 MB   (16,128,T)
  bf16*  p_g     = (bf16*)(big + 16777216 + 12582912 + 8388608);   // 33.6 MB  (4,T,T)
  bf16*  h_b     = (bf16*)regA;
  bf16*  h3_b    = (bf16*)regA;
  bf16*  q_idx_b = (bf16*)regB;
  bf16*  attn_b  = (bf16*)regB;
  bf16*  gate_b  = (bf16*)big;                                     // 32 MB (aliases BIG)
  bf16*  act_b   = (bf16*)(big + (size_t)TSEQ * INTER * 2);        // 32 MB

  // w_uv transpose to bf16 (only weight needing a copy)
  cvt_uv_t<<<1024, 256, 0, stream>>>(w_uv, w_uv_tb);

  // r1 + rmsnorm
  r1_rms<<<TSEQ, 256, 0, stream>>>(hs, res, ln1, r2, h_b);

  // step1 = h @ w_step1^T  (fp32 B on the fly; ragged N=1232 zero-padded to 1280)
  gemm_bt<EPI_F32, false, true><<<dim3(16, 10, 1), 256, 0, stream>>>(
      h_b, w_step1, step1, STEP1_N, HID, HID, HID, STEP1_NP, 0, 0, 0, nullptr, nullptr, 1.f);

  postprocess_step1<<<TSEQ, 256, 0, stream>>>(step1, positions, qln, kvln, q_cn, kv_cn, idx_kb, idx_wf, kfull);

  // q_idx = q_cn @ w_wq_b^T
  gemm_bt<EPI_BF16, false, true><<<dim3(16, 16, 1), 256, 0, stream>>>(
      q_cn, w_wq_b, q_idx_b, 2048, QL, QL, QL, 2048, 0, 0, 0, nullptr, nullptr, 1.f);

  // qf = q_cn @ w_q_b^T
  gemm_bt<EPI_BF16, false, true><<<dim3(16, 24, 1), 256, 0, stream>>>(
      q_cn, w_q_b, qf_b, 3072, QL, QL, QL, 3072, 0, 0, 0, nullptr, nullptr, 1.f);

  rope_q<<<TSEQ, 256, 0, stream>>>(qf_b, positions);

  // indexer scores + causal mask
  iscore_kernel<<<dim3(16, 16), 256, 0, stream>>>(q_idx_b, idx_kb, idx_wf, iscore);

  // exact 512-th largest per row
  radix_topk<<<TSEQ, 256, 0, stream>>>(iscore, thr);

  // k_lat[h] = kv_cn @ w_uk[h]^T -> kfull[:, :128]
  gemm_bt<EPI_BF16, false, true><<<dim3(16, 1, NHH), 256, 0, stream>>>(
      kv_cn, w_uk, kfull, 128, KVL, KVL, KVL, 192,
      0, (long)128 * 512, (long)TSEQ * 192, nullptr, nullptr, 1.f);

  // v_lat_t[h] = w_uv_t[h] @ kv_cn^T  (128 x T)
  gemm_bt<EPI_BF16, false, false><<<dim3(1, 16, NHH), 256, 0, stream>>>(
      w_uv_tb, kv_cn, v_lat_t, TSEQ, KVL, KVL, KVL, TSEQ,
      (long)128 * 512, 0, (long)128 * TSEQ, nullptr, nullptr, 1.f);

  // attention in 4 head-groups of 4 (P buffer reused)
  const float sscale = 0.07216878364870323f;  // (DN+DR)^-0.5
  for (int g = 0; g < NHH / HGRP; g++) {
    const int ho = g * HGRP;
    gemm_bt<EPI_MASK_BF16, true, false><<<dim3(16, 16, HGRP), 256, 0, stream>>>(
        qf_b + 192 * ho, kfull + (long)ho * TSEQ * 192, p_g, TSEQ, 192, 3072, 192, TSEQ,
        192, (long)TSEQ * 192, (long)TSEQ * TSEQ, iscore, thr, sscale);
    softmax_rows<<<dim3(TSEQ, HGRP), 256, 0, stream>>>(p_g);
    gemm_bt<EPI_BF16, false, false><<<dim3(16, 1, HGRP), 256, 0, stream>>>(
        p_g, v_lat_t + (long)ho * 128 * TSEQ, attn_b + 128 * ho, 128, TSEQ, TSEQ, TSEQ, 2048,
        (long)TSEQ * TSEQ, (long)128 * TSEQ, 128, nullptr, nullptr, 1.f);
  }

  // r2 = attn @ w_o^T + r1
  gemm_bt<EPI_ADD_F32, false, true><<<dim3(16, 16, 1), 256, 0, stream>>>(
      attn_b, w_o, r2, HID, 2048, 2048, 2048, HID, 0, 0, 0, r2, nullptr, 1.f);

  rms_h3<<<TSEQ, 256, 0, stream>>>(r2, ln2, h3_b);

  // gate = h3 @ w_gate^T (bf16)
  gemm_bt<EPI_BF16, false, true><<<dim3(16, 64, 1), 256, 0, stream>>>(
      h3_b, w_gate, gate_b, INTER, HID, HID, HID, INTER, 0, 0, 0, nullptr, nullptr, 1.f);

  // act = silu(gate) * (h3 @ w_up^T)
  gemm_bt<EPI_SILUMUL_BF16, false, true><<<dim3(16, 64, 1), 256, 0, stream>>>(
      h3_b, w_up, act_b, INTER, HID, HID, HID, INTER, 0, 0, 0, gate_b, nullptr, 1.f);

  // out = act @ w_down^T (fp32)
  gemm_bt<EPI_F32, false, true><<<dim3(16, 16, 1), 256, 0, stream>>>(
      act_b, w_down, out_f, HID, INTER, INTER, INTER, HID, 0, 0, 0, nullptr, nullptr, 1.f);
}

// Round 3
// 1245.007 us; speedup vs baseline: 1.6910x; 1.6910x over previous
//
#include <hip/hip_runtime.h>
#include <hip/hip_bf16.h>
#include <math.h>

// ---------------- constants ----------------
#define TSEQ 2048
#define HID  2048
#define QL   512
#define KVL  512
#define DR   64
#define DN   128
#define DVV  128
#define NHH  16
#define IDXH 16
#define IDXD 128
#define TOPK 512
#define INTER 8192
#define STEP1_N  1232
#define STEP1_NP 1280
#define HGRP 4   // heads per attention group (4 groups of 4)

#define NEG_FLT_MAX (-3.402823466e38f)

typedef __hip_bfloat16 bf16;
typedef unsigned int u32;
typedef __attribute__((ext_vector_type(8))) short short8;
typedef __attribute__((ext_vector_type(4))) float f32x4;

__device__ __forceinline__ float bf2f(bf16 x) { return __bfloat162float(x); }
__device__ __forceinline__ bf16  f2bf(float x){ return __float2bfloat16(x); }

// async global->LDS, 16 B per lane; lds base must be wave-uniform
__device__ __forceinline__ void async_cp16(const void* g, void* l) {
  __builtin_amdgcn_global_load_lds(
      (const __attribute__((address_space(1))) unsigned int*)g,
      (__attribute__((address_space(3))) unsigned int*)l, 16, 0, 0);
}

// ---------------- block reductions ----------------
__device__ __forceinline__ float block_sum(float v, float* red, int tid) {
  __syncthreads();
#pragma unroll
  for (int o = 32; o > 0; o >>= 1) v += __shfl_down(v, o, 64);
  if ((tid & 63) == 0) red[tid >> 6] = v;
  __syncthreads();
  return red[0] + red[1] + red[2] + red[3];
}
__device__ __forceinline__ float block_max(float v, float* red, int tid) {
  __syncthreads();
#pragma unroll
  for (int o = 32; o > 0; o >>= 1) v = fmaxf(v, __shfl_down(v, o, 64));
  if ((tid & 63) == 0) red[tid >> 6] = v;
  __syncthreads();
  return fmaxf(fmaxf(red[0], red[1]), fmaxf(red[2], red[3]));
}

// ---------------- conversions ----------------
__global__ void cvt_bf16(const float* __restrict__ in, bf16* __restrict__ out, long n) {
  long i = (long)blockIdx.x * blockDim.x + threadIdx.x;
  long stride = (long)gridDim.x * blockDim.x;
  for (; i < n; i += stride) out[i] = f2bf(in[i]);
}
// w_step1 (1232,2048) -> padded (1280,2048) bf16, pad rows zero
__global__ void cvt_step1_w(const float* __restrict__ in, bf16* __restrict__ out) {
  long n = (long)STEP1_NP * HID;
  long i = (long)blockIdx.x * blockDim.x + threadIdx.x;
  long stride = (long)gridDim.x * blockDim.x;
  for (; i < n; i += stride) {
    long r = i >> 11, c = i & 2047;
    out[i] = (r < STEP1_N) ? f2bf(in[r * HID + c]) : f2bf(0.f);
  }
}
// w_uv (16,512,128) -> w_uv_t (16,128,512) bf16
__global__ void cvt_uv_t(const float* __restrict__ in, bf16* __restrict__ out) {
  long n = (long)16 * 512 * 128;
  long i = (long)blockIdx.x * blockDim.x + threadIdx.x;
  long stride = (long)gridDim.x * blockDim.x;
  for (; i < n; i += stride) {
    long h = i >> 16;
    long k = (i >> 7) & 511;
    long v = i & 127;
    out[h * 65536 + v * 512 + k] = f2bf(in[i]);
  }
}

// ---------------- r1 = hs + res ; h = rmsnorm(r1)*ln1 ----------------
__global__ __launch_bounds__(256) void r1_rms(
    const float* __restrict__ hs, const float* __restrict__ res,
    const float* __restrict__ w, float* __restrict__ r1out, bf16* __restrict__ hb) {
  const int t = blockIdx.x, tid = threadIdx.x;
  __shared__ float red[4];
  float loc[8];
  float ss = 0.f;
  const long base = (long)t * HID;
#pragma unroll
  for (int e = 0; e < 8; e++) {
    int i = e * 256 + tid;
    float v = hs[base + i] + res[base + i];
    loc[e] = v; ss += v * v;
    r1out[base + i] = v;
  }
  ss = block_sum(ss, red, tid);
  float rs = rsqrtf(ss / (float)HID + 1e-6f);
#pragma unroll
  for (int e = 0; e < 8; e++) { int i = e * 256 + tid; hb[base + i] = f2bf(loc[e] * rs * w[i]); }
}

// ---------------- rmsnorm(r2)*ln2 -> h3 bf16 ----------------
__global__ __launch_bounds__(256) void rms_h3(
    const float* __restrict__ r2, const float* __restrict__ w, bf16* __restrict__ h3b) {
  const int t = blockIdx.x, tid = threadIdx.x;
  __shared__ float red[4];
  float loc[8];
  float ss = 0.f;
  const long base = (long)t * HID;
#pragma unroll
  for (int e = 0; e < 8; e++) {
    int i = e * 256 + tid;
    float v = r2[base + i];
    loc[e] = v; ss += v * v;
  }
  ss = block_sum(ss, red, tid);
  float rs = rsqrtf(ss / (float)HID + 1e-6f);
#pragma unroll
  for (int e = 0; e < 8; e++) { int i = e * 256 + tid; h3b[base + i] = f2bf(loc[e] * rs * w[i]); }
}

// ---------------- postprocess step1 row ----------------
__global__ __launch_bounds__(256) void postprocess_step1(
    const float* __restrict__ step1, const int* __restrict__ positions,
    const float* __restrict__ q_ln, const float* __restrict__ kv_ln,
    bf16* __restrict__ q_cn, bf16* __restrict__ kv_cn,
    bf16* __restrict__ idx_kb, float* __restrict__ idx_wf,
    bf16* __restrict__ kfull) {
  const int t = blockIdx.x, tid = threadIdx.x;
  __shared__ float red[4];
  const float* row = step1 + (long)t * STEP1_NP;
  float q0 = row[tid], q1 = row[256 + tid];
  float ssq = q0 * q0 + q1 * q1;
  ssq = block_sum(ssq, red, tid);
  float rsq = rsqrtf(ssq / (float)QL + 1e-6f);
  q_cn[(long)t * QL + tid]       = f2bf(q0 * rsq * q_ln[tid]);
  q_cn[(long)t * QL + 256 + tid] = f2bf(q1 * rsq * q_ln[256 + tid]);
  float k0v = row[512 + tid], k1v = row[768 + tid];
  float ssk = k0v * k0v + k1v * k1v;
  ssk = block_sum(ssk, red, tid);
  float rsk = rsqrtf(ssk / (float)KVL + 1e-6f);
  kv_cn[(long)t * KVL + tid]       = f2bf(k0v * rsk * kv_ln[tid]);
  kv_cn[(long)t * KVL + 256 + tid] = f2bf(k1v * rsk * kv_ln[256 + tid]);
  if (tid < 128) idx_kb[(long)t * IDXD + tid] = f2bf(row[1088 + tid]);
  if (tid < 16) idx_wf[(long)t * IDXH + tid] = row[1216 + tid];
  if (tid < 32) {
    const int j = tid;
    float x1 = row[1024 + j], x2 = row[1056 + j];
    float p = (float)positions[t];
    float inv = powf(10000.f, -(float)j * (1.f / 32.f));
    float ang = p * inv;
    float c = cosf(ang), s = sinf(ang);
    bf16 o1 = f2bf(x1 * c - x2 * s), o2 = f2bf(x1 * s + x2 * c);
#pragma unroll
    for (int h = 0; h < NHH; h++) {
      kfull[(long)h * TSEQ * 192 + (long)t * 192 + 128 + j] = o1;
      kfull[(long)h * TSEQ * 192 + (long)t * 192 + 160 + j] = o2;
    }
  }
}

// ---------------- rope on q_pe part of qf (in place, bf16) ----------------
__global__ __launch_bounds__(256) void rope_q(bf16* __restrict__ qf, const int* __restrict__ positions) {
  const int t = blockIdx.x, tid = threadIdx.x;
  const float p = (float)positions[t];
#pragma unroll
  for (int e = 0; e < 2; e++) {
    int id = e * 256 + tid;
    int h = id >> 5, j = id & 31;
    long o = (long)t * 3072 + h * 192 + 128;
    float x1 = bf2f(qf[o + j]), x2 = bf2f(qf[o + 32 + j]);
    float inv = powf(10000.f, -(float)j * (1.f / 32.f));
    float ang = p * inv;
    float c = cosf(ang), s = sinf(ang);
    qf[o + j]      = f2bf(x1 * c - x2 * s);
    qf[o + 32 + j] = f2bf(x1 * s + x2 * c);
  }
}

// ---------------- bf16 GEMM: C = A(128-tiles of M, K; lda) * B(N,K;ldb)^T ----------------
// All M,N multiples of 128; K multiple of 64*SPLITK. Staging via global_load_lds(16B).
// blockIdx.z = batch*SPLITK + split.
enum { EPI_BF16 = 1, EPI_ATOMIC_F32 = 2, EPI_MASK_BF16 = 3, EPI_SILUMUL_BF16 = 4 };

template <int MODE, bool CSKIP, int SPLITK>
__global__ __launch_bounds__(256) void gemm_bt(
    const bf16* __restrict__ A, const bf16* __restrict__ B, void* __restrict__ Cout,
    int K, int lda, int ldb, int ldc,
    long az, long bz, long cz,
    const void* __restrict__ ex0, const float* __restrict__ ex1, float scale) {
  __shared__ __align__(16) bf16 As[128 * 64];
  __shared__ __align__(16) bf16 Bs[128 * 64];
  const int z = blockIdx.z;
  const int batch = z / SPLITK, split = z % SPLITK;
  const int bm = blockIdx.x, bn = blockIdx.y;
  const int tid = threadIdx.x;
  const int lane = tid & 63, wave = tid >> 6;
  const int wm = wave >> 1, wn = wave & 1;
  const int quad = lane >> 4, l16 = lane & 15;
  const long cbase = cz * (long)batch;

  if (CSKIP) {
    if (bn > bm) {  // fully masked upper-triangle tile
      const bf16 nb = f2bf(-INFINITY);
#pragma unroll
      for (int i = 0; i < 4; i++)
#pragma unroll
        for (int j = 0; j < 4; j++) {
          int r0 = bm * 128 + wm * 64 + i * 16 + quad * 4;
          int c = bn * 128 + wn * 64 + j * 16 + l16;
#pragma unroll
          for (int r = 0; r < 4; r++) ((bf16*)Cout)[cbase + (long)(r0 + r) * ldc + c] = nb;
        }
      return;
    }
  }

  const bf16* Ab = A + az * (long)batch;
  const bf16* Bb = B + bz * (long)batch;

  f32x4 acc[4][4];
#pragma unroll
  for (int i = 0; i < 4; i++)
#pragma unroll
    for (int j = 0; j < 4; j++) acc[i][j] = (f32x4){0.f, 0.f, 0.f, 0.f};

  const int srow = lane >> 3;       // 0..7 (row within wave's 8-row band)
  const int scol = (lane & 7) * 8;  // element col in 64-wide K tile

  const int kchunk = K / SPLITK;
  const int ks = split * kchunk, ke = ks + kchunk;

  for (int k0 = ks; k0 < ke; k0 += 64) {
#pragma unroll
    for (int r0 = 0; r0 < 128; r0 += 32) {
      const int row = r0 + wave * 8;
      async_cp16(&Ab[(long)(bm * 128 + row + srow) * lda + k0 + scol], &As[row * 64]);
      async_cp16(&Bb[(long)(bn * 128 + row + srow) * ldb + k0 + scol], &Bs[row * 64]);
    }
    __syncthreads();
#pragma unroll
    for (int kc = 0; kc < 2; kc++) {
      const int kofs = kc * 32 + quad * 8;
      short8 af[4], bfr[4];
#pragma unroll
      for (int i = 0; i < 4; i++) af[i] = *(const short8*)&As[(wm * 64 + i * 16 + l16) * 64 + kofs];
#pragma unroll
      for (int i = 0; i < 4; i++) bfr[i] = *(const short8*)&Bs[(wn * 64 + i * 16 + l16) * 64 + kofs];
#pragma unroll
      for (int i = 0; i < 4; i++)
#pragma unroll
        for (int j = 0; j < 4; j++)
          acc[i][j] = __builtin_amdgcn_mfma_f32_16x16x32_bf16(af[i], bfr[j], acc[i][j], 0, 0, 0);
    }
    __syncthreads();
  }

#pragma unroll
  for (int i = 0; i < 4; i++) {
    const int rb = bm * 128 + wm * 64 + i * 16 + quad * 4;
#pragma unroll
    for (int j = 0; j < 4; j++) {
      const int c = bn * 128 + wn * 64 + j * 16 + l16;
#pragma unroll
      for (int r = 0; r < 4; r++) {
        const int rg = rb + r;
        const float v = acc[i][j][r];
        const long cidx = cbase + (long)rg * ldc + c;
        if (MODE == EPI_BF16) {
          ((bf16*)Cout)[cidx] = f2bf(v);
        } else if (MODE == EPI_ATOMIC_F32) {
          atomicAdd(&((float*)Cout)[cidx], v);
        } else if (MODE == EPI_MASK_BF16) {
          float o;
          if (c > rg || ((const float*)ex0)[(long)rg * 2048 + c] < ex1[rg]) o = -INFINITY;
          else o = v * scale;
          ((bf16*)Cout)[cidx] = f2bf(o);
        } else if (MODE == EPI_SILUMUL_BF16) {
          const float g = bf2f(((const bf16*)ex0)[(long)rg * ldc + c]);
          const float sg = g / (1.f + __expf(-g));
          ((bf16*)Cout)[cidx] = f2bf(sg * v);
        }
      }
    }
  }
}

// ---------------- fused indexer score ----------------
__global__ __launch_bounds__(256) void iscore_kernel(
    const bf16* __restrict__ q_idx, const bf16* __restrict__ idx_k,
    const float* __restrict__ idx_w, float* __restrict__ iscore) {
  __shared__ __align__(16) bf16 As[128 * 64];
  __shared__ __align__(16) bf16 Bs[128 * 128];
  __shared__ float Ws[128 * 16];
  const int bm = blockIdx.x, bn = blockIdx.y;
  const int tid = threadIdx.x;
  const int lane = tid & 63, wave = tid >> 6;
  const int wm = wave >> 1, wn = wave & 1;
  const int quad = lane >> 4, l16 = lane & 15;

  if (bn > bm) {
#pragma unroll
    for (int i = 0; i < 4; i++)
#pragma unroll
      for (int j = 0; j < 4; j++) {
        int r0 = bm * 128 + wm * 64 + i * 16 + quad * 4;
        int c = bn * 128 + wn * 64 + j * 16 + l16;
#pragma unroll
        for (int r = 0; r < 4; r++) iscore[(long)(r0 + r) * 2048 + c] = NEG_FLT_MAX;
      }
    return;
  }

  {  // stage B tile (idx_k 128x128) once, async
#pragma unroll
    for (int r0 = 0; r0 < 128; r0 += 16) {
      const int row = r0 + wave * 4;
      async_cp16(&idx_k[(long)(bn * 128 + row + (lane >> 4)) * IDXD + (lane & 15) * 8],
                 &Bs[row * 128]);
    }
  }
#pragma unroll
  for (int e = 0; e < 8; e++) {
    int ii = e * 256 + tid;
    Ws[ii] = idx_w[(long)(bm * 128) * IDXH + ii];
  }

  float accT[4][4][4];
#pragma unroll
  for (int i = 0; i < 4; i++)
#pragma unroll
    for (int j = 0; j < 4; j++)
#pragma unroll
      for (int r = 0; r < 4; r++) accT[i][j][r] = 0.f;

  const int srow = lane >> 3, scol = (lane & 7) * 8;

  for (int h = 0; h < IDXH; h++) {
    f32x4 acc[4][4];
#pragma unroll
    for (int i = 0; i < 4; i++)
#pragma unroll
      for (int j = 0; j < 4; j++) acc[i][j] = (f32x4){0.f, 0.f, 0.f, 0.f};
    for (int kh = 0; kh < 128; kh += 64) {
      __syncthreads();
#pragma unroll
      for (int r0 = 0; r0 < 128; r0 += 32) {
        const int row = r0 + wave * 8;
        async_cp16(&q_idx[(long)(bm * 128 + row + srow) * 2048 + h * 128 + kh + scol],
                   &As[row * 64]);
      }
      __syncthreads();
#pragma unroll
      for (int kc = 0; kc < 2; kc++) {
        const int kofs = kc * 32 + quad * 8;
        short8 af[4], bfr[4];
#pragma unroll
        for (int i = 0; i < 4; i++) af[i] = *(const short8*)&As[(wm * 64 + i * 16 + l16) * 64 + kofs];
#pragma unroll
        for (int i = 0; i < 4; i++) bfr[i] = *(const short8*)&Bs[(wn * 64 + i * 16 + l16) * 128 + kh + kofs];
#pragma unroll
        for (int i = 0; i < 4; i++)
#pragma unroll
          for (int j = 0; j < 4; j++)
            acc[i][j] = __builtin_amdgcn_mfma_f32_16x16x32_bf16(af[i], bfr[j], acc[i][j], 0, 0, 0);
      }
    }
    const float sc = 0.08838834764831845f;  // 128^-0.5
#pragma unroll
    for (int i = 0; i < 4; i++) {
      int rl = wm * 64 + i * 16 + quad * 4;
#pragma unroll
      for (int r = 0; r < 4; r++) {
        float w = Ws[(rl + r) * 16 + h];
#pragma unroll
        for (int j = 0; j < 4; j++) {
          float v = acc[i][j][r] * sc;
          v = v > 0.f ? v : 0.f;
          accT[i][j][r] += v * w;
        }
      }
    }
  }
#pragma unroll
  for (int i = 0; i < 4; i++) {
    int rb = bm * 128 + wm * 64 + i * 16 + quad * 4;
#pragma unroll
    for (int j = 0; j < 4; j++) {
      int c = bn * 128 + wn * 64 + j * 16 + l16;
#pragma unroll
      for (int r = 0; r < 4; r++) {
        int rg = rb + r;
        iscore[(long)rg * 2048 + c] = (c <= rg) ? accT[i][j][r] : NEG_FLT_MAX;
      }
    }
  }
}

// ---------------- exact k-th largest per row (radix select) ----------------
__global__ __launch_bounds__(256) void radix_topk(const float* __restrict__ iscore, float* __restrict__ thr) {
  __shared__ u32 keys[2048];
  __shared__ int hist[256];
  __shared__ u32 s_prefix;
  __shared__ int s_k;
  const int t = blockIdx.x, tid = threadIdx.x;
#pragma unroll
  for (int e = 0; e < 8; e++) {
    int i = e * 256 + tid;
    u32 b = __float_as_uint(iscore[(long)t * 2048 + i]);
    keys[i] = (b & 0x80000000u) ? ~b : (b | 0x80000000u);
  }
  if (tid == 0) { s_prefix = 0u; s_k = TOPK; }
  u32 prefmask = 0u;
  for (int pass = 0; pass < 4; pass++) {
    const int shift = 24 - pass * 8;
    hist[tid] = 0;
    __syncthreads();
    const u32 pref = s_prefix;
#pragma unroll
    for (int e = 0; e < 8; e++) {
      int i = e * 256 + tid;
      u32 key = keys[i];
      if ((key & prefmask) == pref) atomicAdd(&hist[(key >> shift) & 255], 1);
    }
    __syncthreads();
    if (tid == 0) {
      int k = s_k, d = 255;
      for (; d >= 0; d--) {
        int c = hist[d];
        if (k <= c) break;
        k -= c;
      }
      if (d < 0) d = 0;
      s_prefix = pref | ((u32)d << shift);
      s_k = k;
    }
    prefmask |= (0xFFu << shift);
    __syncthreads();
  }
  if (tid == 0) {
    u32 key = s_prefix;
    u32 b = (key & 0x80000000u) ? (key ^ 0x80000000u) : ~key;
    thr[t] = __uint_as_float(b);
  }
}

// ---------------- in-place row softmax on bf16 (G,T,T) ----------------
__global__ __launch_bounds__(256) void softmax_rows(bf16* __restrict__ p) {
  const int t = blockIdx.x, h = blockIdx.y, tid = threadIdx.x;
  __shared__ float red[4];
  bf16* pr = p + ((long)h * TSEQ + t) * TSEQ;
  float loc[8];
  float mx = -INFINITY;
#pragma unroll
  for (int e = 0; e < 8; e++) {
    float v = bf2f(pr[e * 256 + tid]);
    loc[e] = v;
    mx = fmaxf(mx, v);
  }
  mx = block_max(mx, red, tid);
  float sum = 0.f;
#pragma unroll
  for (int e = 0; e < 8; e++) {
    float d = loc[e] - mx;
    float v = (d < -80.f) ? 0.f : __expf(d);
    loc[e] = v;
    sum += v;
  }
  sum = block_sum(sum, red, tid);
  float inv = 1.f / sum;
#pragma unroll
  for (int e = 0; e < 8; e++) pr[e * 256 + tid] = f2bf(loc[e] * inv);
}

// ---------------- host ----------------
extern "C" void kernel_launch(void* const* d_in, const int* in_sizes, int n_in,
                              void* d_out, int out_size, void* d_ws, size_t ws_size,
                              hipStream_t stream) {
  (void)in_sizes; (void)n_in; (void)out_size; (void)ws_size;
  const int*   positions = (const int*)d_in[0];
  const float* hs        = (const float*)d_in[1];
  const float* res       = (const float*)d_in[2];
  const float* ln1       = (const float*)d_in[3];
  const float* ln2       = (const float*)d_in[4];
  const float* qln       = (const float*)d_in[5];
  const float* kvln      = (const float*)d_in[6];
  const float* w_step1   = (const float*)d_in[7];
  const float* w_wq_b    = (const float*)d_in[8];
  const float* w_q_b     = (const float*)d_in[9];
  const float* w_uk      = (const float*)d_in[10];
  const float* w_uv      = (const float*)d_in[11];
  const float* w_o       = (const float*)d_in[12];
  const float* w_gate    = (const float*)d_in[13];
  const float* w_up      = (const float*)d_in[14];
  const float* w_down    = (const float*)d_in[15];

  float* out_f = (float*)d_out;                    // (T,HID)
  float* r2    = out_f + (long)TSEQ * HID;         // (T,HID) — holds r1; w_o atomically adds

  // ---- workspace pool (~144 MB, explicit aliasing) ----
  char* base = (char*)d_ws;
  size_t off = 0;
  auto alloc = [&](size_t bytes) -> char* {
    char* p = base + off;
    off += (bytes + 255) & ~(size_t)255;
    return p;
  };
  bf16*  w_uv_tb = (bf16*)alloc((size_t)16 * 128 * 512 * 2);       // 2.1 MB
  char*  regA    = alloc((size_t)TSEQ * HID * 2);                  // 8.4 MB: h_b -> h3_b
  float* step1   = (float*)alloc((size_t)TSEQ * STEP1_NP * 4);     // 10.5 MB
  bf16*  q_cn    = (bf16*)alloc((size_t)TSEQ * QL * 2);
  bf16*  kv_cn   = (bf16*)alloc((size_t)TSEQ * KVL * 2);
  bf16*  idx_kb  = (bf16*)alloc((size_t)TSEQ * IDXD * 2);
  float* idx_wf  = (float*)alloc((size_t)TSEQ * IDXH * 4);
  char*  regB    = alloc((size_t)TSEQ * HID * 4);                  // 16.8 MB: q_idx_b -> attn_f32
  char*  regC    = alloc((size_t)TSEQ * 3072 * 2);                 // 12.6 MB: qf_b -> attn_b
  float* thr     = (float*)alloc((size_t)TSEQ * 4);
  // BIG region: [wcvt 33.5 (aliases iscore 16.8) | kfull 12.6 | v_lat 8.4 | p_g 33.6]
  //   MLP phase: gate_b (33.5) overlays kfull/v_lat/p_g start (all dead).
  char*  big     = alloc((size_t)33554432 + 12582912 + 8388608 + (size_t)HGRP * TSEQ * TSEQ * 2);
  bf16*  wcvt    = (bf16*)big;                                     // weight bf16 scratch
  float* iscore  = (float*)big;                                    // aliases wcvt (timeline-safe)
  bf16*  kfull   = (bf16*)(big + 33554432);                        // (16,T,192)
  bf16*  v_lat_t = (bf16*)(big + 33554432 + 12582912);             // (16,128,T)
  bf16*  p_g     = (bf16*)(big + 33554432 + 12582912 + 8388608);   // (HGRP,T,T)
  bf16*  gate_b  = (bf16*)(big + 33554432);                        // MLP phase only
  bf16*  h_b     = (bf16*)regA;
  bf16*  h3_b    = (bf16*)regA;
  bf16*  q_idx_b = (bf16*)regB;
  float* attn_f  = (float*)regB;
  bf16*  qf_b    = (bf16*)regC;
  bf16*  attn_b  = (bf16*)regC;

  // persistent small weight
  cvt_uv_t<<<1024, 256, 0, stream>>>(w_uv, w_uv_tb);

  // r1 + rmsnorm
  r1_rms<<<TSEQ, 256, 0, stream>>>(hs, res, ln1, r2, h_b);

  // step1 = h @ w_step1^T  (split-K=2, atomic into zeroed fp32)
  cvt_step1_w<<<1024, 256, 0, stream>>>(w_step1, wcvt);
  hipMemsetAsync(step1, 0, (size_t)TSEQ * STEP1_NP * 4, stream);
  gemm_bt<EPI_ATOMIC_F32, false, 2><<<dim3(16, 10, 2), 256, 0, stream>>>(
      h_b, wcvt, step1, HID, HID, HID, STEP1_NP, 0, 0, 0, nullptr, nullptr, 1.f);

  postprocess_step1<<<TSEQ, 256, 0, stream>>>(step1, positions, qln, kvln, q_cn, kv_cn, idx_kb, idx_wf, kfull);

  // q_idx = q_cn @ w_wq_b^T
  cvt_bf16<<<512, 256, 0, stream>>>(w_wq_b, wcvt, (long)2048 * 512);
  gemm_bt<EPI_BF16, false, 1><<<dim3(16, 16, 1), 256, 0, stream>>>(
      q_cn, wcvt, q_idx_b, QL, QL, QL, 2048, 0, 0, 0, nullptr, nullptr, 1.f);

  // qf = q_cn @ w_q_b^T
  cvt_bf16<<<512, 256, 0, stream>>>(w_q_b, wcvt, (long)3072 * 512);
  gemm_bt<EPI_BF16, false, 1><<<dim3(16, 24, 1), 256, 0, stream>>>(
      q_cn, wcvt, qf_b, QL, QL, QL, 3072, 0, 0, 0, nullptr, nullptr, 1.f);

  rope_q<<<TSEQ, 256, 0, stream>>>(qf_b, positions);

  // k_lat[h] = kv_cn @ w_uk[h]^T -> kfull[:, :128]
  cvt_bf16<<<512, 256, 0, stream>>>(w_uk, wcvt, (long)16 * 128 * 512);
  gemm_bt<EPI_BF16, false, 1><<<dim3(16, 1, NHH), 256, 0, stream>>>(
      kv_cn, wcvt, kfull, KVL, KVL, KVL, 192,
      0, (long)128 * 512, (long)TSEQ * 192, nullptr, nullptr, 1.f);

  // v_lat_t[h] = w_uv_t[h] @ kv_cn^T  (128 x T)
  gemm_bt<EPI_BF16, false, 1><<<dim3(1, 16, NHH), 256, 0, stream>>>(
      w_uv_tb, kv_cn, v_lat_t, KVL, KVL, KVL, TSEQ,
      (long)128 * 512, 0, (long)128 * TSEQ, nullptr, nullptr, 1.f);

  // indexer scores + causal mask (writes iscore, which aliases wcvt — all cvts above are done)
  iscore_kernel<<<dim3(16, 16), 256, 0, stream>>>(q_idx_b, idx_kb, idx_wf, iscore);

  // exact 512-th largest per row
  radix_topk<<<TSEQ, 256, 0, stream>>>(iscore, thr);

  // attention in 4 head-groups of 4; PV split-K=4 atomic into attn_f (q_idx_b now dead)
  hipMemsetAsync(attn_f, 0, (size_t)TSEQ * HID * 4, stream);
  const float sscale = 0.07216878364870323f;  // (DN+DR)^-0.5
  for (int g = 0; g < NHH / HGRP; g++) {
    const int ho = g * HGRP;
    gemm_bt<EPI_MASK_BF16, true, 1><<<dim3(16, 16, HGRP), 256, 0, stream>>>(
        qf_b + 192 * ho, kfull + (long)ho * TSEQ * 192, p_g, 192, 3072, 192, TSEQ,
        192, (long)TSEQ * 192, (long)TSEQ * TSEQ, iscore, thr, sscale);
    softmax_rows<<<dim3(TSEQ, HGRP), 256, 0, stream>>>(p_g);
    gemm_bt<EPI_ATOMIC_F32, false, 4><<<dim3(16, 1, HGRP * 4), 256, 0, stream>>>(
        p_g, v_lat_t + (long)ho * 128 * TSEQ, attn_f + 128 * ho, TSEQ, TSEQ, TSEQ, 2048,
        (long)TSEQ * TSEQ, (long)128 * TSEQ, 128, nullptr, nullptr, 1.f);
  }

  // attn -> bf16 (qf_b dead)
  cvt_bf16<<<1024, 256, 0, stream>>>(attn_f, attn_b, (long)TSEQ * HID);

  // r2 += attn @ w_o^T  (r2 holds r1; split-K=2 atomic)
  cvt_bf16<<<1024, 256, 0, stream>>>(w_o, wcvt, (long)2048 * 2048);
  gemm_bt<EPI_ATOMIC_F32, false, 2><<<dim3(16, 16, 2), 256, 0, stream>>>(
      attn_b, wcvt, r2, 2048, 2048, 2048, HID, 0, 0, 0, nullptr, nullptr, 1.f);

  rms_h3<<<TSEQ, 256, 0, stream>>>(r2, ln2, h3_b);

  // gate = h3 @ w_gate^T (bf16) -> gate_b
  cvt_bf16<<<2048, 256, 0, stream>>>(w_gate, wcvt, (long)INTER * HID);
  gemm_bt<EPI_BF16, false, 1><<<dim3(16, 64, 1), 256, 0, stream>>>(
      h3_b, wcvt, gate_b, HID, HID, HID, INTER, 0, 0, 0, nullptr, nullptr, 1.f);

  // act = silu(gate) * (h3 @ w_up^T) -> gate_b in place (per-element read-then-write)
  cvt_bf16<<<2048, 256, 0, stream>>>(w_up, wcvt, (long)INTER * HID);
  gemm_bt<EPI_SILUMUL_BF16, false, 1><<<dim3(16, 64, 1), 256, 0, stream>>>(
      h3_b, wcvt, gate_b, HID, HID, HID, INTER, 0, 0, 0, gate_b, nullptr, 1.f);

  // out = act @ w_down^T (split-K=4, atomic into zeroed out)
  cvt_bf16<<<2048, 256, 0, stream>>>(w_down, wcvt, (long)HID * INTER);
  hipMemsetAsync(out_f, 0, (size_t)TSEQ * HID * 4, stream);
  gemm_bt<EPI_ATOMIC_F32, false, 4><<<dim3(16, 16, 4), 256, 0, stream>>>(
      gate_b, wcvt, out_f, INTER, INTER, INTER, HID, 0, 0, 0, nullptr, nullptr, 1.f);
}